// Round 16
// baseline (166.666 us; speedup 1.0000x reference)
//
#include <hip/hip_runtime.h>
#include <stdint.h>

#define DEVI __device__ __forceinline__

constexpr int Bb = 2, NQ = 1024, S = 4096, H = 1024, NH = 16, HD = 64;
constexpr int NSPLIT = 4, SLEN = S / NSPLIT;

typedef __bf16 bf16x8 __attribute__((ext_vector_type(8)));
typedef float f32x4 __attribute__((ext_vector_type(4)));
typedef int i32x4 __attribute__((ext_vector_type(4)));
typedef unsigned short u16;
typedef u16 u16x8 __attribute__((ext_vector_type(8)));

DEVI u16 f2bf(float f) {
  union { float f; unsigned u; } v; v.f = f;
  unsigned r = (v.u + 0x7fffu + ((v.u >> 16) & 1u)) >> 16;
  return (u16)r;
}

DEVI float bf2f(u16 x) {
  union { unsigned u; float f; } v; v.u = ((unsigned)x) << 16;
  return v.f;
}

DEVI float fexp2(float x) {
#if __has_builtin(__builtin_amdgcn_exp2f)
  return __builtin_amdgcn_exp2f(x);
#else
  return exp2f(x);
#endif
}

DEVI void gload_lds16(const void* g, void* lds) {
  __builtin_amdgcn_global_load_lds(
      (const __attribute__((address_space(1))) void*)(uintptr_t)g,
      (__attribute__((address_space(3))) void*)(uint32_t)(uintptr_t)lds,
      16, 0, 0);
}

// ---------------- fused prep: mask->f32 bias | LN(q) | LN(kv) | W^T --------
DEVI void ln_body(const float* __restrict__ x, const float* __restrict__ gamma,
                  const float* __restrict__ beta, u16* __restrict__ out, int row) {
  int lane = threadIdx.x & 63;
  const float4* xr = (const float4*)(x + (size_t)row * H);
  float4 v[4];
  float s = 0.f, s2 = 0.f;
#pragma unroll
  for (int i = 0; i < 4; ++i) {
    v[i] = xr[lane + i * 64];
    s += v[i].x + v[i].y + v[i].z + v[i].w;
    s2 += v[i].x * v[i].x + v[i].y * v[i].y + v[i].z * v[i].z + v[i].w * v[i].w;
  }
#pragma unroll
  for (int d = 1; d < 64; d <<= 1) { s += __shfl_xor(s, d); s2 += __shfl_xor(s2, d); }
  float mu = s * (1.f / H);
  float rstd = rsqrtf(s2 * (1.f / H) - mu * mu + 1e-6f);
  u16* orow = out + (size_t)row * H;
  const float4* g4 = (const float4*)gamma;
  const float4* b4 = (const float4*)beta;
#pragma unroll
  for (int i = 0; i < 4; ++i) {
    float4 g = g4[lane + i * 64], bb = b4[lane + i * 64];
    ushort4 o;
    o.x = f2bf((v[i].x - mu) * rstd * g.x + bb.x);
    o.y = f2bf((v[i].y - mu) * rstd * g.y + bb.y);
    o.z = f2bf((v[i].z - mu) * rstd * g.z + bb.z);
    o.w = f2bf((v[i].w - mu) * rstd * g.w + bb.w);
    *(ushort4*)(orow + (size_t)(lane + i * 64) * 4) = o;
  }
}

__global__ __launch_bounds__(256) void prep_kernel(
    const unsigned char* __restrict__ mraw, float* __restrict__ maskF,
    const float* __restrict__ queries, const float* __restrict__ keys_values,
    const float* __restrict__ gamma, const float* __restrict__ beta,
    u16* __restrict__ Xq, u16* __restrict__ Xkv,
    const float* __restrict__ W_qkv, const float* __restrict__ W_out,
    u16* __restrict__ Wtq, u16* __restrict__ Wto) {
  __shared__ int isByte;
  __shared__ float tile[32][33];
  const int b = blockIdx.x;
  if (b == 0) {
    if (threadIdx.x == 0) isByte = 0;
    __syncthreads();
    int any = 0;
    for (int p = threadIdx.x; p < Bb * S; p += 256)
      if ((p & 3) && mraw[p]) any = 1;
    if (any) atomicOr(&isByte, 1);
    __syncthreads();
    const int bytemode = isByte;
    for (int i = threadIdx.x; i < Bb * S; i += 256) {
      bool on = bytemode ? (mraw[i] != 0) : (((const int*)mraw)[i] != 0);
      maskF[i] = on ? 0.f : -1e30f;
    }
  } else if (b < 513) {
    ln_body(queries, gamma, beta, Xq, (b - 1) * 4 + (threadIdx.x >> 6));
  } else if (b < 2561) {
    ln_body(keys_values, gamma, beta, Xkv, (b - 513) * 4 + (threadIdx.x >> 6));
  } else {
    const float* in; u16* out; int C, t;
    if (b < 5633) { t = b - 2561; in = W_qkv; out = Wtq; C = 3 * H; }
    else          { t = b - 5633; in = W_out; out = Wto; C = H; }
    const int nbx = C / 32;
    int c0 = (t % nbx) * 32, r0 = (t / nbx) * 32;
    int tx = threadIdx.x & 31, ty = threadIdx.x >> 5;
#pragma unroll
    for (int i = 0; i < 32; i += 8)
      tile[ty + i][tx] = in[(size_t)(r0 + ty + i) * C + c0 + tx];
    __syncthreads();
#pragma unroll
    for (int i = 0; i < 32; i += 8)
      out[(size_t)(c0 + ty + i) * H + r0 + tx] = f2bf(tile[tx][ty + i]);
  }
}

// ------- 128^2 ring GEMM (BK=32, 4-buffer counted-vmcnt), three epilogues --
// EPI 0: -> Qbuf bf16 [B][NH][NQ][HD], pre-scaled by 0.125*log2(e). 2D grid.
// EPI 1: -> f32 out [M][1024]. 2D grid.
// EPI 2: -> K [B][NH][S][HD] | V^T [B][NH][HD][S]. Flat grid 1024,
//         XCD-chunked: xcd=bid&7 owns by in [xcd*8, xcd*8+8) -> 2MB A L2-res.
template <int EPI>
__global__ __launch_bounds__(256, 2) void gemm128_kernel(
    const u16* __restrict__ A, const u16* __restrict__ Bt,
    const float* __restrict__ bias, void* __restrict__ outp) {
  __shared__ __align__(16) u16 Abuf[4][128 * 32];
  __shared__ __align__(16) u16 Bbuf[4][128 * 32];
  const int tid = threadIdx.x, wid = tid >> 6, lane = tid & 63;
  const int fr = lane & 15, fq = lane >> 4;
  const int wr = (wid >> 1) * 64, wc = (wid & 1) * 64;
  int brow, bcol;
  if constexpr (EPI == 2) {
    const int bid = blockIdx.x;
    const int xcd = bid & 7, loc = bid >> 3;
    brow = (xcd * 8 + (loc & 7)) * 128;   // by: 0..63
    bcol = (loc >> 3) * 128;              // bx: 0..15
  } else {
    brow = blockIdx.y * 128;
    bcol = blockIdx.x * 128;
  }
  const u16* Ag = A + (size_t)brow * 1024;
  const u16* Bg = Bt + (size_t)bcol * 1024;

  f32x4 acc[4][4] = {};

  auto stage = [&](int tt) {
    const int k0 = tt * 32;
    u16* Ad = &Abuf[tt & 3][0];
    u16* Bd = &Bbuf[tt & 3][0];
#pragma unroll
    for (int l = 0; l < 2; ++l) {
      int ci = tid + l * 256;
      int row = ci >> 2, ch = ci & 3;
      int chs = ch ^ ((row >> 1) & 3);
      gload_lds16(Ag + (size_t)row * 1024 + k0 + chs * 8, Ad + ci * 8);
      gload_lds16(Bg + (size_t)row * 1024 + k0 + chs * 8, Bd + ci * 8);
    }
  };

#define OUT_ITER(T, VM)                                                         \
  {                                                                             \
    asm volatile("s_waitcnt vmcnt(" #VM ")" ::: "memory");                      \
    __syncthreads();                                                            \
    const u16* Ac = &Abuf[(T) & 3][0];                                          \
    const u16* Bc = &Bbuf[(T) & 3][0];                                          \
    bf16x8 af[4], bfv[4];                                                       \
    _Pragma("unroll") for (int m = 0; m < 4; ++m) {                             \
      int row = wr + m * 16 + fr;                                               \
      af[m] = *(const bf16x8*)(Ac + row * 32 + (fq ^ ((row >> 1) & 3)) * 8);    \
    }                                                                           \
    _Pragma("unroll") for (int n = 0; n < 4; ++n) {                             \
      int row = wc + n * 16 + fr;                                               \
      bfv[n] = *(const bf16x8*)(Bc + row * 32 + (fq ^ ((row >> 1) & 3)) * 8);   \
    }                                                                           \
    if ((T) + 3 < 32) stage((T) + 3);                                           \
    __builtin_amdgcn_s_setprio(1);                                              \
    _Pragma("unroll") for (int m = 0; m < 4; ++m)                               \
      _Pragma("unroll") for (int n = 0; n < 4; ++n)                             \
        acc[m][n] = __builtin_amdgcn_mfma_f32_16x16x32_bf16(af[m], bfv[n], acc[m][n], 0, 0, 0); \
    __builtin_amdgcn_s_setprio(0);                                              \
  }

  stage(0);
  stage(1);
  stage(2);
  for (int t = 0; t < 29; ++t) OUT_ITER(t, 8)
  OUT_ITER(29, 8)
  OUT_ITER(30, 4)
  OUT_ITER(31, 0)
#undef OUT_ITER

  constexpr float QSCALE = 0.125f * 1.4426950408889634f;
#pragma unroll
  for (int m = 0; m < 4; ++m)
#pragma unroll
    for (int n = 0; n < 4; ++n) {
      const int c = bcol + wc + n * 16 + fr;
      const int r0 = brow + wr + m * 16 + fq * 4;
      const float bv = bias[c];
      if constexpr (EPI == 0) {
#pragma unroll
        for (int i = 0; i < 4; ++i) {
          int r = r0 + i;
          ((u16*)outp)[((((size_t)(r >> 10)) * NH + (c >> 6)) * NQ + (r & (NQ - 1))) * HD + (c & 63)] =
              f2bf((acc[m][n][i] + bv) * QSCALE);
        }
      } else if constexpr (EPI == 1) {
#pragma unroll
        for (int i = 0; i < 4; ++i)
          ((float*)outp)[(size_t)(r0 + i) * H + c] = acc[m][n][i] + bv;
      } else {
        if (c >= 1024) {  // V^T [B][NH][HD][S], 4 consecutive kv packed
          int bb = r0 >> 12, kv = r0 & (S - 1);
          int cc = c - 1024, head = cc >> 6, d = cc & 63;
          ushort4 o;
          o.x = f2bf(acc[m][n][0] + bv);
          o.y = f2bf(acc[m][n][1] + bv);
          o.z = f2bf(acc[m][n][2] + bv);
          o.w = f2bf(acc[m][n][3] + bv);
          u16* vb = (u16*)outp + (size_t)Bb * NH * S * HD;
          *(ushort4*)(vb + (((size_t)(bb * NH + head)) * HD + d) * S + kv) = o;
        } else {  // K [B][NH][S][HD]
#pragma unroll
          for (int i = 0; i < 4; ++i) {
            int r = r0 + i;
            ((u16*)outp)[((((size_t)(r >> 12)) * NH + (c >> 6)) * S + (r & (S - 1))) * HD + (c & 63)] =
                f2bf(acc[m][n][i] + bv);
          }
        }
      }
    }
}

// -------- flash attention: 8 waves, QBLK=256, 2 q-groups/wave, KVBLK=64 ----
// R15-verified config (best: 64 us). Mask bias from global f32 (L2).
__global__ __launch_bounds__(512, 4) void attn_kernel(
    const u16* __restrict__ Qb, const u16* __restrict__ Kb,
    const u16* __restrict__ Vt, const float* __restrict__ maskF,
    u16* __restrict__ Opart, float2* __restrict__ ml) {
  __shared__ __align__(16) char smem[34816];
  u16* Ktile = (u16*)smem;
  u16* Vtile = Ktile + 8192;
  const int bflat = blockIdx.x;
  const int r = bflat & 7, idx = bflat >> 3;
  const int q0 = (idx & 3) * 256;
  const int g = (idx >> 2) * 8 + r;
  const int bh = g & 31, z = g >> 5;
  const int b = bh >> 4, kv0 = z * SLEN;
  const int tid = threadIdx.x, w = tid >> 6, lane = tid & 63;
  const int fr = lane & 15, fq = lane >> 4, fr7 = fr & 7;
  const u16* QgA = Qb + ((size_t)bh * NQ + q0 + w * 32) * HD;
  const u16* QgB = QgA + 16 * HD;
  const u16* Kg = Kb + (size_t)bh * S * HD;
  const u16* Vg = Vt + (size_t)bh * HD * S;
  const float* mgf = maskF + (size_t)b * S + kv0 + fq * 4;

  const int rs = tid >> 3, gs = (tid & 7) ^ (rs & 7);

  bf16x8 qfA0 = *(const bf16x8*)(QgA + fr * HD + fq * 8);
  bf16x8 qfA1 = *(const bf16x8*)(QgA + fr * HD + 32 + fq * 8);
  bf16x8 qfB0 = *(const bf16x8*)(QgB + fr * HD + fq * 8);
  bf16x8 qfB1 = *(const bf16x8*)(QgB + fr * HD + 32 + fq * 8);

  const int A0 = ((((fq << 1)) & 3) * 16 + fr) << 2;
  const int A1 = ((((fq << 1) + 1) & 3) * 16 + fr) << 2;
  const bool lofq = (fq < 2);

  f32x4 oaccA[4] = {}, oaccB[4] = {};
  float mrowA = -1e30f, lrowA = 0.f, mrowB = -1e30f, lrowB = 0.f;

  gload_lds16(Kg + (size_t)(kv0 + rs) * HD + gs * 8, Ktile + tid * 8);
  gload_lds16(Vg + (size_t)rs * S + kv0 + gs * 8, Vtile + tid * 8);
  asm volatile("s_waitcnt vmcnt(0)" ::: "memory");
  __syncthreads();

  int cur = 0;
  for (int kt = 0; kt < SLEN; kt += 64) {
    const int nb = cur ^ 1, kn = kt + 64;
    if (kn < SLEN) {
      gload_lds16(Kg + (size_t)(kv0 + kn + rs) * HD + gs * 8, Ktile + nb * 4096 + tid * 8);
      gload_lds16(Vg + (size_t)rs * S + kv0 + kn + gs * 8, Vtile + nb * 4096 + tid * 8);
    }

    const u16* Kc = Ktile + cur * 4096;
    const u16* Vc = Vtile + cur * 4096;

    float4 mb0 = *(const float4*)(mgf + kt);
    float4 mb1 = *(const float4*)(mgf + kt + 16);
    float4 mb2 = *(const float4*)(mgf + kt + 32);
    float4 mb3 = *(const float4*)(mgf + kt + 48);

    float svA[4][4], svB[4][4];
    __builtin_amdgcn_s_setprio(1);
#pragma unroll
    for (int nt = 0; nt < 4; ++nt) {
      const u16* kb2 = Kc + (nt * 16 + fr) * 64;
      bf16x8 k0v = *(const bf16x8*)(kb2 + ((fq) ^ fr7) * 8);
      bf16x8 k1v = *(const bf16x8*)(kb2 + ((4 + fq) ^ fr7) * 8);
      f32x4 tA = {}, tB = {};
      tA = __builtin_amdgcn_mfma_f32_16x16x32_bf16(k0v, qfA0, tA, 0, 0, 0);
      tA = __builtin_amdgcn_mfma_f32_16x16x32_bf16(k1v, qfA1, tA, 0, 0, 0);
      tB = __builtin_amdgcn_mfma_f32_16x16x32_bf16(k0v, qfB0, tB, 0, 0, 0);
      tB = __builtin_amdgcn_mfma_f32_16x16x32_bf16(k1v, qfB1, tB, 0, 0, 0);
      float4 mb = (nt == 0) ? mb0 : (nt == 1) ? mb1 : (nt == 2) ? mb2 : mb3;
      svA[nt][0] = tA[0] + mb.x; svA[nt][1] = tA[1] + mb.y;
      svA[nt][2] = tA[2] + mb.z; svA[nt][3] = tA[3] + mb.w;
      svB[nt][0] = tB[0] + mb.x; svB[nt][1] = tB[1] + mb.y;
      svB[nt][2] = tB[2] + mb.z; svB[nt][3] = tB[3] + mb.w;
    }
    __builtin_amdgcn_s_setprio(0);

    float pmaxA, pmaxB;
    {
      float a0 = fmaxf(fmaxf(svA[0][0], svA[0][1]), fmaxf(svA[0][2], svA[0][3]));
      float a1 = fmaxf(fmaxf(svA[1][0], svA[1][1]), fmaxf(svA[1][2], svA[1][3]));
      float a2 = fmaxf(fmaxf(svA[2][0], svA[2][1]), fmaxf(svA[2][2], svA[2][3]));
      float a3 = fmaxf(fmaxf(svA[3][0], svA[3][1]), fmaxf(svA[3][2], svA[3][3]));
      pmaxA = fmaxf(fmaxf(a0, a1), fmaxf(a2, a3));
      float b0 = fmaxf(fmaxf(svB[0][0], svB[0][1]), fmaxf(svB[0][2], svB[0][3]));
      float b1 = fmaxf(fmaxf(svB[1][0], svB[1][1]), fmaxf(svB[1][2], svB[1][3]));
      float b2 = fmaxf(fmaxf(svB[2][0], svB[2][1]), fmaxf(svB[2][2], svB[2][3]));
      float b3 = fmaxf(fmaxf(svB[3][0], svB[3][1]), fmaxf(svB[3][2], svB[3][3]));
      pmaxB = fmaxf(fmaxf(b0, b1), fmaxf(b2, b3));
    }
    if (__any(pmaxA > mrowA + 12.f)) {
      pmaxA = fmaxf(pmaxA, __shfl_xor(pmaxA, 16));
      pmaxA = fmaxf(pmaxA, __shfl_xor(pmaxA, 32));
      float nm = fmaxf(mrowA, pmaxA);
      float al = fexp2(mrowA - nm);
      mrowA = nm; lrowA *= al;
#pragma unroll
      for (int nt = 0; nt < 4; ++nt)
#pragma unroll
        for (int i = 0; i < 4; ++i) oaccA[nt][i] *= al;
    }
    if (__any(pmaxB > mrowB + 12.f)) {
      pmaxB = fmaxf(pmaxB, __shfl_xor(pmaxB, 16));
      pmaxB = fmaxf(pmaxB, __shfl_xor(pmaxB, 32));
      float nm = fmaxf(mrowB, pmaxB);
      float al = fexp2(mrowB - nm);
      mrowB = nm; lrowB *= al;
#pragma unroll
      for (int nt = 0; nt < 4; ++nt)
#pragma unroll
        for (int i = 0; i < 4; ++i) oaccB[nt][i] *= al;
    }

    float pA[4][4], pB[4][4];
#pragma unroll
    for (int nt = 0; nt < 4; ++nt)
#pragma unroll
      for (int i = 0; i < 4; ++i) {
        pA[nt][i] = fexp2(svA[nt][i] - mrowA);
        pB[nt][i] = fexp2(svB[nt][i] - mrowB);
      }
    {
      float s0 = (pA[0][0] + pA[0][1]) + (pA[0][2] + pA[0][3]);
      float s1 = (pA[1][0] + pA[1][1]) + (pA[1][2] + pA[1][3]);
      float s2 = (pA[2][0] + pA[2][1]) + (pA[2][2] + pA[2][3]);
      float s3 = (pA[3][0] + pA[3][1]) + (pA[3][2] + pA[3][3]);
      lrowA += (s0 + s1) + (s2 + s3);
      float t0 = (pB[0][0] + pB[0][1]) + (pB[0][2] + pB[0][3]);
      float t1 = (pB[1][0] + pB[1][1]) + (pB[1][2] + pB[1][3]);
      float t2 = (pB[2][0] + pB[2][1]) + (pB[2][2] + pB[2][3]);
      float t3 = (pB[3][0] + pB[3][1]) + (pB[3][2] + pB[3][3]);
      lrowB += (t0 + t1) + (t2 + t3);
    }

    int pkA[4][2], pkB[4][2];
#pragma unroll
    for (int nt = 0; nt < 4; ++nt) {
      asm("v_cvt_pk_bf16_f32 %0, %1, %2" : "=v"(pkA[nt][0]) : "v"(pA[nt][0]), "v"(pA[nt][1]));
      asm("v_cvt_pk_bf16_f32 %0, %1, %2" : "=v"(pkA[nt][1]) : "v"(pA[nt][2]), "v"(pA[nt][3]));
      asm("v_cvt_pk_bf16_f32 %0, %1, %2" : "=v"(pkB[nt][0]) : "v"(pB[nt][0]), "v"(pB[nt][1]));
      asm("v_cvt_pk_bf16_f32 %0, %1, %2" : "=v"(pkB[nt][1]) : "v"(pB[nt][2]), "v"(pB[nt][3]));
    }

#pragma unroll
    for (int b2 = 0; b2 < 2; ++b2) {
      i32x4 wvA, wvB;
      {
        int w0a = __builtin_amdgcn_ds_bpermute(A0, pkA[2 * b2][0]);
        int w0b = __builtin_amdgcn_ds_bpermute(A0, pkA[2 * b2 + 1][0]);
        int w1a = __builtin_amdgcn_ds_bpermute(A0, pkA[2 * b2][1]);
        int w1b = __builtin_amdgcn_ds_bpermute(A0, pkA[2 * b2 + 1][1]);
        int w2a = __builtin_amdgcn_ds_bpermute(A1, pkA[2 * b2][0]);
        int w2b = __builtin_amdgcn_ds_bpermute(A1, pkA[2 * b2 + 1][0]);
        int w3a = __builtin_amdgcn_ds_bpermute(A1, pkA[2 * b2][1]);
        int w3b = __builtin_amdgcn_ds_bpermute(A1, pkA[2 * b2 + 1][1]);
        wvA[0] = lofq ? w0a : w0b;
        wvA[1] = lofq ? w1a : w1b;
        wvA[2] = lofq ? w2a : w2b;
        wvA[3] = lofq ? w3a : w3b;
      }
      {
        int w0a = __builtin_amdgcn_ds_bpermute(A0, pkB[2 * b2][0]);
        int w0b = __builtin_amdgcn_ds_bpermute(A0, pkB[2 * b2 + 1][0]);
        int w1a = __builtin_amdgcn_ds_bpermute(A0, pkB[2 * b2][1]);
        int w1b = __builtin_amdgcn_ds_bpermute(A0, pkB[2 * b2 + 1][1]);
        int w2a = __builtin_amdgcn_ds_bpermute(A1, pkB[2 * b2][0]);
        int w2b = __builtin_amdgcn_ds_bpermute(A1, pkB[2 * b2 + 1][0]);
        int w3a = __builtin_amdgcn_ds_bpermute(A1, pkB[2 * b2][1]);
        int w3b = __builtin_amdgcn_ds_bpermute(A1, pkB[2 * b2 + 1][1]);
        wvB[0] = lofq ? w0a : w0b;
        wvB[1] = lofq ? w1a : w1b;
        wvB[2] = lofq ? w2a : w2b;
        wvB[3] = lofq ? w3a : w3b;
      }
      bf16x8 pfragA = __builtin_bit_cast(bf16x8, wvA);
      bf16x8 pfragB = __builtin_bit_cast(bf16x8, wvB);
      __builtin_amdgcn_s_setprio(1);
#pragma unroll
      for (int nt = 0; nt < 4; ++nt) {
        const u16* vb2 = Vc + (nt * 16 + fr) * 64;
        bf16x8 vf = *(const bf16x8*)(vb2 + ((b2 * 4 + fq) ^ fr7) * 8);
        oaccA[nt] = __builtin_amdgcn_mfma_f32_16x16x32_bf16(vf, pfragA, oaccA[nt], 0, 0, 0);
        oaccB[nt] = __builtin_amdgcn_mfma_f32_16x16x32_bf16(vf, pfragB, oaccB[nt], 0, 0, 0);
      }
      __builtin_amdgcn_s_setprio(0);
    }

    asm volatile("s_waitcnt vmcnt(0)" ::: "memory");
    __syncthreads();
    cur = nb;
  }

  lrowA += __shfl_xor(lrowA, 16);
  lrowA += __shfl_xor(lrowA, 32);
  lrowB += __shfl_xor(lrowB, 16);
  lrowB += __shfl_xor(lrowB, 32);
  if (fq == 0) {
    ml[((size_t)z * 32 + bh) * NQ + q0 + w * 32 + fr] = float2{mrowA, lrowA};
    ml[((size_t)z * 32 + bh) * NQ + q0 + w * 32 + 16 + fr] = float2{mrowB, lrowB};
  }

  float* tb = (float*)smem + w * 1088;
  const int qloc = lane >> 2, dl = lane & 3;
#pragma unroll
  for (int gsel = 0; gsel < 2; ++gsel) {
    const f32x4* oc = gsel ? oaccB : oaccA;
#pragma unroll
    for (int nt = 0; nt < 4; ++nt)
#pragma unroll
      for (int i = 0; i < 4; ++i)
        tb[fr * 68 + nt * 16 + fq * 4 + i] = oc[nt][i];
    const float* trow = tb + qloc * 68 + dl * 16;
    u16* gdst = Opart +
        (((size_t)z * 32 + bh) * NQ + q0 + w * 32 + gsel * 16 + qloc) * 64 + dl * 16;
    u16x8 o0, o1;
#pragma unroll
    for (int j = 0; j < 8; ++j) {
      o0[j] = f2bf(trow[j]);
      o1[j] = f2bf(trow[8 + j]);
    }
    *(u16x8*)gdst = o0;
    *(u16x8*)(gdst + 8) = o1;
  }
}

// ---------------- combine split partials -> bf16 Aout ----------------------
__global__ __launch_bounds__(256) void combine_kernel(
    const u16* __restrict__ Opart, const float2* __restrict__ ml,
    u16* __restrict__ out) {
  const int bh = blockIdx.y, b = bh >> 4, h = bh & 15;
  const int q = blockIdx.x * 64 + (threadIdx.x >> 2);
  const int dl = threadIdx.x & 3;
  float2 mm[NSPLIT];
  float M = -1e30f;
#pragma unroll
  for (int zz = 0; zz < NSPLIT; ++zz) {
    mm[zz] = ml[((size_t)zz * 32 + bh) * NQ + q];
    M = fmaxf(M, mm[zz].x);
  }
  float wz[NSPLIT], lsum = 0.f;
#pragma unroll
  for (int zz = 0; zz < NSPLIT; ++zz) {
    wz[zz] = fexp2(mm[zz].x - M);
    lsum += mm[zz].y * wz[zz];
  }
  const float inv = 1.f / lsum;
  float acc[16] = {};
#pragma unroll
  for (int zz = 0; zz < NSPLIT; ++zz) {
    const u16* op = Opart + (((size_t)zz * 32 + bh) * NQ + q) * 64 + dl * 16;
    u16x8 a0 = *(const u16x8*)op;
    u16x8 a1 = *(const u16x8*)(op + 8);
    float wi = wz[zz] * inv;
#pragma unroll
    for (int j = 0; j < 8; ++j) {
      acc[j] += wi * bf2f(a0[j]);
      acc[8 + j] += wi * bf2f(a1[j]);
    }
  }
  u16* orow = out + ((size_t)b * NQ + q) * H + h * HD + dl * 16;
  u16x8 o0, o1;
#pragma unroll
  for (int j = 0; j < 8; ++j) {
    o0[j] = f2bf(acc[j]);
    o1[j] = f2bf(acc[8 + j]);
  }
  *(u16x8*)orow = o0;
  *(u16x8*)(orow + 8) = o1;
}

// ---------------------------------------------------------------------------
extern "C" void kernel_launch(void* const* d_in, const int* in_sizes, int n_in,
                              void* d_out, int out_size, void* d_ws, size_t ws_size,
                              hipStream_t stream) {
  const float* queries = (const float*)d_in[0];
  const float* keys_values = (const float*)d_in[1];
  const void* amask = d_in[2];
  const float* W_qkv = (const float*)d_in[3];
  const float* b_qkv = (const float*)d_in[4];
  const float* W_out = (const float*)d_in[5];
  const float* b_out = (const float*)d_in[6];
  const float* gamma = (const float*)d_in[7];
  const float* beta = (const float*)d_in[8];

  char* ws = (char*)d_ws;
  float* maskF = (float*)ws;                                 // 32 KB f32 bias
  u16* Xq = (u16*)(ws + 32768);                              // [2048][1024]
  u16* Xkv = Xq + (size_t)Bb * NQ * H;                       // [8192][1024]
  u16* Wtq = Xkv + (size_t)Bb * S * H;                       // [3072][1024]
  u16* Wto = Wtq + (size_t)3 * H * H;                        // [1024][1024]
  u16* Qbuf = Wto + (size_t)H * H;                           // [B][NH][NQ][HD]
  u16* Kbuf = Qbuf + (size_t)Bb * NQ * H;                    // [B][NH][S][HD]; V^T follows
  u16* Aout = Kbuf + (size_t)2 * Bb * S * H;                 // [2048][1024]
  u16* Opart = (u16*)(ws + 32768);                           // 16 MB bf16 overlay
  float2* ml = (float2*)((char*)Opart + (size_t)NSPLIT * 32 * NQ * 64 * 2);  // 1 MB

  hipLaunchKernelGGL(prep_kernel, dim3(6657), dim3(256), 0, stream,
                     (const unsigned char*)amask, maskF, queries, keys_values,
                     gamma, beta, Xq, Xkv, W_qkv, W_out, Wtq, Wto);
  hipLaunchKernelGGL(gemm128_kernel<2>, dim3(1024), dim3(256), 0, stream,
                     Xkv, Wtq + (size_t)H * H, b_qkv + H, (void*)Kbuf);
  hipLaunchKernelGGL(gemm128_kernel<0>, dim3(8, 16), dim3(256), 0, stream,
                     Xq, Wtq, b_qkv, (void*)Qbuf);
  hipLaunchKernelGGL(attn_kernel, dim3(NQ / 256 * Bb * NH * NSPLIT), dim3(512), 0, stream,
                     Qbuf, Kbuf, Kbuf + (size_t)Bb * S * H, maskF, Opart, ml);
  hipLaunchKernelGGL(combine_kernel, dim3(NQ / 64, Bb * NH), dim3(256), 0, stream,
                     Opart, ml, Aout);
  hipLaunchKernelGGL(gemm128_kernel<1>, dim3(8, 16), dim3(256), 0, stream,
                     Aout, Wto, b_out, (void*)d_out);
}

// Round 17
// 156.471 us; speedup vs baseline: 1.0652x; 1.0652x over previous
//
#include <hip/hip_runtime.h>
#include <stdint.h>

#define DEVI __device__ __forceinline__

constexpr int Bb = 2, NQ = 1024, S = 4096, H = 1024, NH = 16, HD = 64;
constexpr int NSPLIT = 4, SLEN = S / NSPLIT;

typedef __bf16 bf16x8 __attribute__((ext_vector_type(8)));
typedef float f32x4 __attribute__((ext_vector_type(4)));
typedef int i32x4 __attribute__((ext_vector_type(4)));
typedef unsigned short u16;
typedef u16 u16x8 __attribute__((ext_vector_type(8)));

DEVI u16 f2bf(float f) {
  union { float f; unsigned u; } v; v.f = f;
  unsigned r = (v.u + 0x7fffu + ((v.u >> 16) & 1u)) >> 16;
  return (u16)r;
}

DEVI float bf2f(u16 x) {
  union { unsigned u; float f; } v; v.u = ((unsigned)x) << 16;
  return v.f;
}

DEVI float fexp2(float x) {
#if __has_builtin(__builtin_amdgcn_exp2f)
  return __builtin_amdgcn_exp2f(x);
#else
  return exp2f(x);
#endif
}

DEVI void gload_lds16(const void* g, void* lds) {
  __builtin_amdgcn_global_load_lds(
      (const __attribute__((address_space(1))) void*)(uintptr_t)g,
      (__attribute__((address_space(3))) void*)(uint32_t)(uintptr_t)lds,
      16, 0, 0);
}

// ---------------- fused prep: mask->f32 bias | LN(q) | LN(kv) | W^T --------
DEVI void ln_body(const float* __restrict__ x, const float* __restrict__ gamma,
                  const float* __restrict__ beta, u16* __restrict__ out, int row) {
  int lane = threadIdx.x & 63;
  const float4* xr = (const float4*)(x + (size_t)row * H);
  float4 v[4];
  float s = 0.f, s2 = 0.f;
#pragma unroll
  for (int i = 0; i < 4; ++i) {
    v[i] = xr[lane + i * 64];
    s += v[i].x + v[i].y + v[i].z + v[i].w;
    s2 += v[i].x * v[i].x + v[i].y * v[i].y + v[i].z * v[i].z + v[i].w * v[i].w;
  }
#pragma unroll
  for (int d = 1; d < 64; d <<= 1) { s += __shfl_xor(s, d); s2 += __shfl_xor(s2, d); }
  float mu = s * (1.f / H);
  float rstd = rsqrtf(s2 * (1.f / H) - mu * mu + 1e-6f);
  u16* orow = out + (size_t)row * H;
  const float4* g4 = (const float4*)gamma;
  const float4* b4 = (const float4*)beta;
#pragma unroll
  for (int i = 0; i < 4; ++i) {
    float4 g = g4[lane + i * 64], bb = b4[lane + i * 64];
    ushort4 o;
    o.x = f2bf((v[i].x - mu) * rstd * g.x + bb.x);
    o.y = f2bf((v[i].y - mu) * rstd * g.y + bb.y);
    o.z = f2bf((v[i].z - mu) * rstd * g.z + bb.z);
    o.w = f2bf((v[i].w - mu) * rstd * g.w + bb.w);
    *(ushort4*)(orow + (size_t)(lane + i * 64) * 4) = o;
  }
}

__global__ __launch_bounds__(256) void prep_kernel(
    const unsigned char* __restrict__ mraw, float* __restrict__ maskF,
    const float* __restrict__ queries, const float* __restrict__ keys_values,
    const float* __restrict__ gamma, const float* __restrict__ beta,
    u16* __restrict__ Xq, u16* __restrict__ Xkv,
    const float* __restrict__ W_qkv, const float* __restrict__ W_out,
    u16* __restrict__ Wtq, u16* __restrict__ Wto) {
  __shared__ int isByte;
  __shared__ float tile[32][33];
  const int b = blockIdx.x;
  if (b == 0) {
    if (threadIdx.x == 0) isByte = 0;
    __syncthreads();
    int any = 0;
    for (int p = threadIdx.x; p < Bb * S; p += 256)
      if ((p & 3) && mraw[p]) any = 1;
    if (any) atomicOr(&isByte, 1);
    __syncthreads();
    const int bytemode = isByte;
    for (int i = threadIdx.x; i < Bb * S; i += 256) {
      bool on = bytemode ? (mraw[i] != 0) : (((const int*)mraw)[i] != 0);
      maskF[i] = on ? 0.f : -1e30f;
    }
  } else if (b < 513) {
    ln_body(queries, gamma, beta, Xq, (b - 1) * 4 + (threadIdx.x >> 6));
  } else if (b < 2561) {
    ln_body(keys_values, gamma, beta, Xkv, (b - 513) * 4 + (threadIdx.x >> 6));
  } else {
    const float* in; u16* out; int C, t;
    if (b < 5633) { t = b - 2561; in = W_qkv; out = Wtq; C = 3 * H; }
    else          { t = b - 5633; in = W_out; out = Wto; C = H; }
    const int nbx = C / 32;
    int c0 = (t % nbx) * 32, r0 = (t / nbx) * 32;
    int tx = threadIdx.x & 31, ty = threadIdx.x >> 5;
#pragma unroll
    for (int i = 0; i < 32; i += 8)
      tile[ty + i][tx] = in[(size_t)(r0 + ty + i) * C + c0 + tx];
    __syncthreads();
#pragma unroll
    for (int i = 0; i < 32; i += 8)
      out[(size_t)(c0 + ty + i) * H + r0 + tx] = f2bf(tile[tx][ty + i]);
  }
}

// ---------- KV projection GEMM: 256^2, BK=32, 4-buffer counted-vmcnt ring --
// (R15-verified.) Grid exactly 256 (uniform). XCD-chunked block map.
__global__ __launch_bounds__(512, 2) void gemm_kv_kernel(
    const u16* __restrict__ Xkv, const u16* __restrict__ WtqKV,
    const float* __restrict__ bias, u16* __restrict__ KVbuf) {
  __shared__ __align__(16) u16 Abuf[4][256 * 32];
  __shared__ __align__(16) u16 Bbuf[4][256 * 32];
  const int tid = threadIdx.x, wid = tid >> 6, lane = tid & 63;
  const int fr = lane & 15, fq = lane >> 4;
  const int wr = (wid >> 2) * 128, wc = (wid & 3) * 64;
  const int bid = blockIdx.x;
  const int xcd = bid & 7, loc = bid >> 3;
  const int by = xcd * 4 + (loc & 3), bx = loc >> 2;  // by:0..31, bx:0..7
  const u16* Ag = Xkv + (size_t)(by * 256) * 1024;
  const u16* Bg = WtqKV + (size_t)(bx * 256) * 1024;

  f32x4 acc[8][4] = {};

  auto stage = [&](int tt) {
    const int k0 = tt * 32;
    u16* Ad = &Abuf[tt & 3][0];
    u16* Bd = &Bbuf[tt & 3][0];
#pragma unroll
    for (int l = 0; l < 2; ++l) {
      int ci = tid + l * 512;
      int row = ci >> 2, ch = ci & 3;
      int chs = ch ^ ((row >> 1) & 3);
      gload_lds16(Ag + (size_t)row * 1024 + k0 + chs * 8, Ad + ci * 8);
      gload_lds16(Bg + (size_t)row * 1024 + k0 + chs * 8, Bd + ci * 8);
    }
  };

#define KV_ITER(T, VM)                                                          \
  {                                                                             \
    asm volatile("s_waitcnt vmcnt(" #VM ")" ::: "memory");                      \
    __syncthreads();                                                            \
    const u16* Ac = &Abuf[(T) & 3][0];                                          \
    const u16* Bc = &Bbuf[(T) & 3][0];                                          \
    bf16x8 af[8], bfv[4];                                                       \
    _Pragma("unroll") for (int m = 0; m < 8; ++m) {                             \
      int row = wr + m * 16 + fr;                                               \
      af[m] = *(const bf16x8*)(Ac + row * 32 + (fq ^ ((row >> 1) & 3)) * 8);    \
    }                                                                           \
    _Pragma("unroll") for (int n = 0; n < 4; ++n) {                             \
      int row = wc + n * 16 + fr;                                               \
      bfv[n] = *(const bf16x8*)(Bc + row * 32 + (fq ^ ((row >> 1) & 3)) * 8);   \
    }                                                                           \
    if ((T) + 3 < 32) stage((T) + 3);                                           \
    __builtin_amdgcn_s_setprio(1);                                              \
    _Pragma("unroll") for (int m = 0; m < 8; ++m)                               \
      _Pragma("unroll") for (int n = 0; n < 4; ++n)                             \
        acc[m][n] = __builtin_amdgcn_mfma_f32_16x16x32_bf16(af[m], bfv[n], acc[m][n], 0, 0, 0); \
    __builtin_amdgcn_s_setprio(0);                                              \
  }

  stage(0);
  stage(1);
  stage(2);
  for (int t = 0; t < 29; ++t) KV_ITER(t, 8)
  KV_ITER(29, 8)
  KV_ITER(30, 4)
  KV_ITER(31, 0)
#undef KV_ITER

#pragma unroll
  for (int m = 0; m < 8; ++m)
#pragma unroll
    for (int n = 0; n < 4; ++n) {
      const int c = bx * 256 + wc + n * 16 + fr;
      const int r0 = by * 256 + wr + m * 16 + fq * 4;
      const float bv = bias[c];
      if (c >= 1024) {  // V^T [B][NH][HD][S]
        int bb = r0 >> 12, kv = r0 & (S - 1);
        int cc = c - 1024, head = cc >> 6, d = cc & 63;
        ushort4 o;
        o.x = f2bf(acc[m][n][0] + bv);
        o.y = f2bf(acc[m][n][1] + bv);
        o.z = f2bf(acc[m][n][2] + bv);
        o.w = f2bf(acc[m][n][3] + bv);
        u16* vb = KVbuf + (size_t)Bb * NH * S * HD;
        *(ushort4*)(vb + (((size_t)(bb * NH + head)) * HD + d) * S + kv) = o;
      } else {  // K [B][NH][S][HD]
#pragma unroll
        for (int i = 0; i < 4; ++i) {
          int r = r0 + i;
          KVbuf[((((size_t)(r >> 12)) * NH + (c >> 6)) * S + (r & (S - 1))) * HD + (c & 63)] =
              f2bf(acc[m][n][i] + bv);
        }
      }
    }
}

// ------- 64x128 ring GEMM (BK=32, 4-buffer, vmcnt 6/3/0), two epilogues ----
// Grid (8, 32) = 256 blocks -> every CU busy (vs 128-block 128^2 version).
// 4 waves: wr=(wid>>1)*32 (2 M-frags), wc=(wid&1)*64 (4 N-frags).
// Stage = 3 loads/thread (A:1, B:2) -> steady-state vmcnt(6), tail 6/3/0.
template <int EPI>
__global__ __launch_bounds__(256, 3) void gemm64_kernel(
    const u16* __restrict__ A, const u16* __restrict__ Bt,
    const float* __restrict__ bias, void* __restrict__ outp) {
  __shared__ __align__(16) u16 Abuf[4][64 * 32];
  __shared__ __align__(16) u16 Bbuf[4][128 * 32];
  const int tid = threadIdx.x, wid = tid >> 6, lane = tid & 63;
  const int fr = lane & 15, fq = lane >> 4;
  const int wr = (wid >> 1) * 32, wc = (wid & 1) * 64;
  const int brow = blockIdx.y * 64, bcol = blockIdx.x * 128;
  const u16* Ag = A + (size_t)brow * 1024;
  const u16* Bg = Bt + (size_t)bcol * 1024;

  f32x4 acc[2][4] = {};

  auto stage = [&](int tt) {
    const int k0 = tt * 32;
    u16* Ad = &Abuf[tt & 3][0];
    u16* Bd = &Bbuf[tt & 3][0];
    {
      int row = tid >> 2, ch = tid & 3;
      int chs = ch ^ ((row >> 1) & 3);
      gload_lds16(Ag + (size_t)row * 1024 + k0 + chs * 8, Ad + tid * 8);
    }
#pragma unroll
    for (int l = 0; l < 2; ++l) {
      int ci = tid + l * 256;
      int row = ci >> 2, ch = ci & 3;
      int chs = ch ^ ((row >> 1) & 3);
      gload_lds16(Bg + (size_t)row * 1024 + k0 + chs * 8, Bd + ci * 8);
    }
  };

#define G64_ITER(T, VM)                                                         \
  {                                                                             \
    asm volatile("s_waitcnt vmcnt(" #VM ")" ::: "memory");                      \
    __syncthreads();                                                            \
    const u16* Ac = &Abuf[(T) & 3][0];                                          \
    const u16* Bc = &Bbuf[(T) & 3][0];                                          \
    bf16x8 af[2], bfv[4];                                                       \
    _Pragma("unroll") for (int m = 0; m < 2; ++m) {                             \
      int row = wr + m * 16 + fr;                                               \
      af[m] = *(const bf16x8*)(Ac + row * 32 + (fq ^ ((row >> 1) & 3)) * 8);    \
    }                                                                           \
    _Pragma("unroll") for (int n = 0; n < 4; ++n) {                             \
      int row = wc + n * 16 + fr;                                               \
      bfv[n] = *(const bf16x8*)(Bc + row * 32 + (fq ^ ((row >> 1) & 3)) * 8);   \
    }                                                                           \
    if ((T) + 3 < 32) stage((T) + 3);                                           \
    __builtin_amdgcn_s_setprio(1);                                              \
    _Pragma("unroll") for (int m = 0; m < 2; ++m)                               \
      _Pragma("unroll") for (int n = 0; n < 4; ++n)                             \
        acc[m][n] = __builtin_amdgcn_mfma_f32_16x16x32_bf16(af[m], bfv[n], acc[m][n], 0, 0, 0); \
    __builtin_amdgcn_s_setprio(0);                                              \
  }

  stage(0);
  stage(1);
  stage(2);
  for (int t = 0; t < 29; ++t) G64_ITER(t, 6)
  G64_ITER(29, 6)
  G64_ITER(30, 3)
  G64_ITER(31, 0)
#undef G64_ITER

  constexpr float QSCALE = 0.125f * 1.4426950408889634f;
#pragma unroll
  for (int m = 0; m < 2; ++m)
#pragma unroll
    for (int n = 0; n < 4; ++n) {
      const int c = bcol + wc + n * 16 + fr;
      const int r0 = brow + wr + m * 16 + fq * 4;
      const float bv = bias[c];
#pragma unroll
      for (int i = 0; i < 4; ++i) {
        int r = r0 + i;
        float val = acc[m][n][i] + bv;
        if constexpr (EPI == 0) {
          ((u16*)outp)[((((size_t)(r >> 10)) * NH + (c >> 6)) * NQ + (r & (NQ - 1))) * HD + (c & 63)] =
              f2bf(val * QSCALE);
        } else {
          ((float*)outp)[(size_t)r * H + c] = val;
        }
      }
    }
}

// -------- flash attention: 8 waves, QBLK=256, 2 q-groups/wave, KVBLK=64 ----
// (R15-verified, best 64 us.) Mask bias from global f32 (L2).
__global__ __launch_bounds__(512, 4) void attn_kernel(
    const u16* __restrict__ Qb, const u16* __restrict__ Kb,
    const u16* __restrict__ Vt, const float* __restrict__ maskF,
    u16* __restrict__ Opart, float2* __restrict__ ml) {
  __shared__ __align__(16) char smem[34816];
  u16* Ktile = (u16*)smem;
  u16* Vtile = Ktile + 8192;
  const int bflat = blockIdx.x;
  const int r = bflat & 7, idx = bflat >> 3;
  const int q0 = (idx & 3) * 256;
  const int g = (idx >> 2) * 8 + r;
  const int bh = g & 31, z = g >> 5;
  const int b = bh >> 4, kv0 = z * SLEN;
  const int tid = threadIdx.x, w = tid >> 6, lane = tid & 63;
  const int fr = lane & 15, fq = lane >> 4, fr7 = fr & 7;
  const u16* QgA = Qb + ((size_t)bh * NQ + q0 + w * 32) * HD;
  const u16* QgB = QgA + 16 * HD;
  const u16* Kg = Kb + (size_t)bh * S * HD;
  const u16* Vg = Vt + (size_t)bh * HD * S;
  const float* mgf = maskF + (size_t)b * S + kv0 + fq * 4;

  const int rs = tid >> 3, gs = (tid & 7) ^ (rs & 7);

  bf16x8 qfA0 = *(const bf16x8*)(QgA + fr * HD + fq * 8);
  bf16x8 qfA1 = *(const bf16x8*)(QgA + fr * HD + 32 + fq * 8);
  bf16x8 qfB0 = *(const bf16x8*)(QgB + fr * HD + fq * 8);
  bf16x8 qfB1 = *(const bf16x8*)(QgB + fr * HD + 32 + fq * 8);

  const int A0 = ((((fq << 1)) & 3) * 16 + fr) << 2;
  const int A1 = ((((fq << 1) + 1) & 3) * 16 + fr) << 2;
  const bool lofq = (fq < 2);

  f32x4 oaccA[4] = {}, oaccB[4] = {};
  float mrowA = -1e30f, lrowA = 0.f, mrowB = -1e30f, lrowB = 0.f;

  gload_lds16(Kg + (size_t)(kv0 + rs) * HD + gs * 8, Ktile + tid * 8);
  gload_lds16(Vg + (size_t)rs * S + kv0 + gs * 8, Vtile + tid * 8);
  asm volatile("s_waitcnt vmcnt(0)" ::: "memory");
  __syncthreads();

  int cur = 0;
  for (int kt = 0; kt < SLEN; kt += 64) {
    const int nb = cur ^ 1, kn = kt + 64;
    if (kn < SLEN) {
      gload_lds16(Kg + (size_t)(kv0 + kn + rs) * HD + gs * 8, Ktile + nb * 4096 + tid * 8);
      gload_lds16(Vg + (size_t)rs * S + kv0 + kn + gs * 8, Vtile + nb * 4096 + tid * 8);
    }

    const u16* Kc = Ktile + cur * 4096;
    const u16* Vc = Vtile + cur * 4096;

    float4 mb0 = *(const float4*)(mgf + kt);
    float4 mb1 = *(const float4*)(mgf + kt + 16);
    float4 mb2 = *(const float4*)(mgf + kt + 32);
    float4 mb3 = *(const float4*)(mgf + kt + 48);

    float svA[4][4], svB[4][4];
    __builtin_amdgcn_s_setprio(1);
#pragma unroll
    for (int nt = 0; nt < 4; ++nt) {
      const u16* kb2 = Kc + (nt * 16 + fr) * 64;
      bf16x8 k0v = *(const bf16x8*)(kb2 + ((fq) ^ fr7) * 8);
      bf16x8 k1v = *(const bf16x8*)(kb2 + ((4 + fq) ^ fr7) * 8);
      f32x4 tA = {}, tB = {};
      tA = __builtin_amdgcn_mfma_f32_16x16x32_bf16(k0v, qfA0, tA, 0, 0, 0);
      tA = __builtin_amdgcn_mfma_f32_16x16x32_bf16(k1v, qfA1, tA, 0, 0, 0);
      tB = __builtin_amdgcn_mfma_f32_16x16x32_bf16(k0v, qfB0, tB, 0, 0, 0);
      tB = __builtin_amdgcn_mfma_f32_16x16x32_bf16(k1v, qfB1, tB, 0, 0, 0);
      float4 mb = (nt == 0) ? mb0 : (nt == 1) ? mb1 : (nt == 2) ? mb2 : mb3;
      svA[nt][0] = tA[0] + mb.x; svA[nt][1] = tA[1] + mb.y;
      svA[nt][2] = tA[2] + mb.z; svA[nt][3] = tA[3] + mb.w;
      svB[nt][0] = tB[0] + mb.x; svB[nt][1] = tB[1] + mb.y;
      svB[nt][2] = tB[2] + mb.z; svB[nt][3] = tB[3] + mb.w;
    }
    __builtin_amdgcn_s_setprio(0);

    float pmaxA, pmaxB;
    {
      float a0 = fmaxf(fmaxf(svA[0][0], svA[0][1]), fmaxf(svA[0][2], svA[0][3]));
      float a1 = fmaxf(fmaxf(svA[1][0], svA[1][1]), fmaxf(svA[1][2], svA[1][3]));
      float a2 = fmaxf(fmaxf(svA[2][0], svA[2][1]), fmaxf(svA[2][2], svA[2][3]));
      float a3 = fmaxf(fmaxf(svA[3][0], svA[3][1]), fmaxf(svA[3][2], svA[3][3]));
      pmaxA = fmaxf(fmaxf(a0, a1), fmaxf(a2, a3));
      float b0 = fmaxf(fmaxf(svB[0][0], svB[0][1]), fmaxf(svB[0][2], svB[0][3]));
      float b1 = fmaxf(fmaxf(svB[1][0], svB[1][1]), fmaxf(svB[1][2], svB[1][3]));
      float b2 = fmaxf(fmaxf(svB[2][0], svB[2][1]), fmaxf(svB[2][2], svB[2][3]));
      float b3 = fmaxf(fmaxf(svB[3][0], svB[3][1]), fmaxf(svB[3][2], svB[3][3]));
      pmaxB = fmaxf(fmaxf(b0, b1), fmaxf(b2, b3));
    }
    if (__any(pmaxA > mrowA + 12.f)) {
      pmaxA = fmaxf(pmaxA, __shfl_xor(pmaxA, 16));
      pmaxA = fmaxf(pmaxA, __shfl_xor(pmaxA, 32));
      float nm = fmaxf(mrowA, pmaxA);
      float al = fexp2(mrowA - nm);
      mrowA = nm; lrowA *= al;
#pragma unroll
      for (int nt = 0; nt < 4; ++nt)
#pragma unroll
        for (int i = 0; i < 4; ++i) oaccA[nt][i] *= al;
    }
    if (__any(pmaxB > mrowB + 12.f)) {
      pmaxB = fmaxf(pmaxB, __shfl_xor(pmaxB, 16));
      pmaxB = fmaxf(pmaxB, __shfl_xor(pmaxB, 32));
      float nm = fmaxf(mrowB, pmaxB);
      float al = fexp2(mrowB - nm);
      mrowB = nm; lrowB *= al;
#pragma unroll
      for (int nt = 0; nt < 4; ++nt)
#pragma unroll
        for (int i = 0; i < 4; ++i) oaccB[nt][i] *= al;
    }

    float pA[4][4], pB[4][4];
#pragma unroll
    for (int nt = 0; nt < 4; ++nt)
#pragma unroll
      for (int i = 0; i < 4; ++i) {
        pA[nt][i] = fexp2(svA[nt][i] - mrowA);
        pB[nt][i] = fexp2(svB[nt][i] - mrowB);
      }
    {
      float s0 = (pA[0][0] + pA[0][1]) + (pA[0][2] + pA[0][3]);
      float s1 = (pA[1][0] + pA[1][1]) + (pA[1][2] + pA[1][3]);
      float s2 = (pA[2][0] + pA[2][1]) + (pA[2][2] + pA[2][3]);
      float s3 = (pA[3][0] + pA[3][1]) + (pA[3][2] + pA[3][3]);
      lrowA += (s0 + s1) + (s2 + s3);
      float t0 = (pB[0][0] + pB[0][1]) + (pB[0][2] + pB[0][3]);
      float t1 = (pB[1][0] + pB[1][1]) + (pB[1][2] + pB[1][3]);
      float t2 = (pB[2][0] + pB[2][1]) + (pB[2][2] + pB[2][3]);
      float t3 = (pB[3][0] + pB[3][1]) + (pB[3][2] + pB[3][3]);
      lrowB += (t0 + t1) + (t2 + t3);
    }

    int pkA[4][2], pkB[4][2];
#pragma unroll
    for (int nt = 0; nt < 4; ++nt) {
      asm("v_cvt_pk_bf16_f32 %0, %1, %2" : "=v"(pkA[nt][0]) : "v"(pA[nt][0]), "v"(pA[nt][1]));
      asm("v_cvt_pk_bf16_f32 %0, %1, %2" : "=v"(pkA[nt][1]) : "v"(pA[nt][2]), "v"(pA[nt][3]));
      asm("v_cvt_pk_bf16_f32 %0, %1, %2" : "=v"(pkB[nt][0]) : "v"(pB[nt][0]), "v"(pB[nt][1]));
      asm("v_cvt_pk_bf16_f32 %0, %1, %2" : "=v"(pkB[nt][1]) : "v"(pB[nt][2]), "v"(pB[nt][3]));
    }

#pragma unroll
    for (int b2 = 0; b2 < 2; ++b2) {
      i32x4 wvA, wvB;
      {
        int w0a = __builtin_amdgcn_ds_bpermute(A0, pkA[2 * b2][0]);
        int w0b = __builtin_amdgcn_ds_bpermute(A0, pkA[2 * b2 + 1][0]);
        int w1a = __builtin_amdgcn_ds_bpermute(A0, pkA[2 * b2][1]);
        int w1b = __builtin_amdgcn_ds_bpermute(A0, pkA[2 * b2 + 1][1]);
        int w2a = __builtin_amdgcn_ds_bpermute(A1, pkA[2 * b2][0]);
        int w2b = __builtin_amdgcn_ds_bpermute(A1, pkA[2 * b2 + 1][0]);
        int w3a = __builtin_amdgcn_ds_bpermute(A1, pkA[2 * b2][1]);
        int w3b = __builtin_amdgcn_ds_bpermute(A1, pkA[2 * b2 + 1][1]);
        wvA[0] = lofq ? w0a : w0b;
        wvA[1] = lofq ? w1a : w1b;
        wvA[2] = lofq ? w2a : w2b;
        wvA[3] = lofq ? w3a : w3b;
      }
      {
        int w0a = __builtin_amdgcn_ds_bpermute(A0, pkB[2 * b2][0]);
        int w0b = __builtin_amdgcn_ds_bpermute(A0, pkB[2 * b2 + 1][0]);
        int w1a = __builtin_amdgcn_ds_bpermute(A0, pkB[2 * b2][1]);
        int w1b = __builtin_amdgcn_ds_bpermute(A0, pkB[2 * b2 + 1][1]);
        int w2a = __builtin_amdgcn_ds_bpermute(A1, pkB[2 * b2][0]);
        int w2b = __builtin_amdgcn_ds_bpermute(A1, pkB[2 * b2 + 1][0]);
        int w3a = __builtin_amdgcn_ds_bpermute(A1, pkB[2 * b2][1]);
        int w3b = __builtin_amdgcn_ds_bpermute(A1, pkB[2 * b2 + 1][1]);
        wvB[0] = lofq ? w0a : w0b;
        wvB[1] = lofq ? w1a : w1b;
        wvB[2] = lofq ? w2a : w2b;
        wvB[3] = lofq ? w3a : w3b;
      }
      bf16x8 pfragA = __builtin_bit_cast(bf16x8, wvA);
      bf16x8 pfragB = __builtin_bit_cast(bf16x8, wvB);
      __builtin_amdgcn_s_setprio(1);
#pragma unroll
      for (int nt = 0; nt < 4; ++nt) {
        const u16* vb2 = Vc + (nt * 16 + fr) * 64;
        bf16x8 vf = *(const bf16x8*)(vb2 + ((b2 * 4 + fq) ^ fr7) * 8);
        oaccA[nt] = __builtin_amdgcn_mfma_f32_16x16x32_bf16(vf, pfragA, oaccA[nt], 0, 0, 0);
        oaccB[nt] = __builtin_amdgcn_mfma_f32_16x16x32_bf16(vf, pfragB, oaccB[nt], 0, 0, 0);
      }
      __builtin_amdgcn_s_setprio(0);
    }

    asm volatile("s_waitcnt vmcnt(0)" ::: "memory");
    __syncthreads();
    cur = nb;
  }

  lrowA += __shfl_xor(lrowA, 16);
  lrowA += __shfl_xor(lrowA, 32);
  lrowB += __shfl_xor(lrowB, 16);
  lrowB += __shfl_xor(lrowB, 32);
  if (fq == 0) {
    ml[((size_t)z * 32 + bh) * NQ + q0 + w * 32 + fr] = float2{mrowA, lrowA};
    ml[((size_t)z * 32 + bh) * NQ + q0 + w * 32 + 16 + fr] = float2{mrowB, lrowB};
  }

  float* tb = (float*)smem + w * 1088;
  const int qloc = lane >> 2, dl = lane & 3;
#pragma unroll
  for (int gsel = 0; gsel < 2; ++gsel) {
    const f32x4* oc = gsel ? oaccB : oaccA;
#pragma unroll
    for (int nt = 0; nt < 4; ++nt)
#pragma unroll
      for (int i = 0; i < 4; ++i)
        tb[fr * 68 + nt * 16 + fq * 4 + i] = oc[nt][i];
    const float* trow = tb + qloc * 68 + dl * 16;
    u16* gdst = Opart +
        (((size_t)z * 32 + bh) * NQ + q0 + w * 32 + gsel * 16 + qloc) * 64 + dl * 16;
    u16x8 o0, o1;
#pragma unroll
    for (int j = 0; j < 8; ++j) {
      o0[j] = f2bf(trow[j]);
      o1[j] = f2bf(trow[8 + j]);
    }
    *(u16x8*)gdst = o0;
    *(u16x8*)(gdst + 8) = o1;
  }
}

// ---------------- combine split partials -> bf16 Aout ----------------------
__global__ __launch_bounds__(256) void combine_kernel(
    const u16* __restrict__ Opart, const float2* __restrict__ ml,
    u16* __restrict__ out) {
  const int bh = blockIdx.y, b = bh >> 4, h = bh & 15;
  const int q = blockIdx.x * 64 + (threadIdx.x >> 2);
  const int dl = threadIdx.x & 3;
  float2 mm[NSPLIT];
  float M = -1e30f;
#pragma unroll
  for (int zz = 0; zz < NSPLIT; ++zz) {
    mm[zz] = ml[((size_t)zz * 32 + bh) * NQ + q];
    M = fmaxf(M, mm[zz].x);
  }
  float wz[NSPLIT], lsum = 0.f;
#pragma unroll
  for (int zz = 0; zz < NSPLIT; ++zz) {
    wz[zz] = fexp2(mm[zz].x - M);
    lsum += mm[zz].y * wz[zz];
  }
  const float inv = 1.f / lsum;
  float acc[16] = {};
#pragma unroll
  for (int zz = 0; zz < NSPLIT; ++zz) {
    const u16* op = Opart + (((size_t)zz * 32 + bh) * NQ + q) * 64 + dl * 16;
    u16x8 a0 = *(const u16x8*)op;
    u16x8 a1 = *(const u16x8*)(op + 8);
    float wi = wz[zz] * inv;
#pragma unroll
    for (int j = 0; j < 8; ++j) {
      acc[j] += wi * bf2f(a0[j]);
      acc[8 + j] += wi * bf2f(a1[j]);
    }
  }
  u16* orow = out + ((size_t)b * NQ + q) * H + h * HD + dl * 16;
  u16x8 o0, o1;
#pragma unroll
  for (int j = 0; j < 8; ++j) {
    o0[j] = f2bf(acc[j]);
    o1[j] = f2bf(acc[8 + j]);
  }
  *(u16x8*)orow = o0;
  *(u16x8*)(orow + 8) = o1;
}

// ---------------------------------------------------------------------------
extern "C" void kernel_launch(void* const* d_in, const int* in_sizes, int n_in,
                              void* d_out, int out_size, void* d_ws, size_t ws_size,
                              hipStream_t stream) {
  const float* queries = (const float*)d_in[0];
  const float* keys_values = (const float*)d_in[1];
  const void* amask = d_in[2];
  const float* W_qkv = (const float*)d_in[3];
  const float* b_qkv = (const float*)d_in[4];
  const float* W_out = (const float*)d_in[5];
  const float* b_out = (const float*)d_in[6];
  const float* gamma = (const float*)d_in[7];
  const float* beta = (const float*)d_in[8];

  char* ws = (char*)d_ws;
  float* maskF = (float*)ws;                                 // 32 KB f32 bias
  u16* Xq = (u16*)(ws + 32768);                              // [2048][1024]
  u16* Xkv = Xq + (size_t)Bb * NQ * H;                       // [8192][1024]
  u16* Wtq = Xkv + (size_t)Bb * S * H;                       // [3072][1024]
  u16* Wto = Wtq + (size_t)3 * H * H;                        // [1024][1024]
  u16* Qbuf = Wto + (size_t)H * H;                           // [B][NH][NQ][HD]
  u16* Kbuf = Qbuf + (size_t)Bb * NQ * H;                    // [B][NH][S][HD]; V^T follows
  u16* Aout = Kbuf + (size_t)2 * Bb * S * H;                 // [2048][1024]
  u16* Opart = (u16*)(ws + 32768);                           // 16 MB bf16 overlay
  float2* ml = (float2*)((char*)Opart + (size_t)NSPLIT * 32 * NQ * 64 * 2);  // 1 MB

  hipLaunchKernelGGL(prep_kernel, dim3(6657), dim3(256), 0, stream,
                     (const unsigned char*)amask, maskF, queries, keys_values,
                     gamma, beta, Xq, Xkv, W_qkv, W_out, Wtq, Wto);
  hipLaunchKernelGGL(gemm_kv_kernel, dim3(256), dim3(512), 0, stream,
                     Xkv, Wtq + (size_t)H * H, b_qkv + H, Kbuf);
  hipLaunchKernelGGL(gemm64_kernel<0>, dim3(8, 32), dim3(256), 0, stream,
                     Xq, Wtq, b_qkv, (void*)Qbuf);
  hipLaunchKernelGGL(attn_kernel, dim3(NQ / 256 * Bb * NH * NSPLIT), dim3(512), 0, stream,
                     Qbuf, Kbuf, Kbuf + (size_t)Bb * S * H, maskF, Opart, ml);
  hipLaunchKernelGGL(combine_kernel, dim3(NQ / 64, Bb * NH), dim3(256), 0, stream,
                     Opart, ml, Aout);
  hipLaunchKernelGGL(gemm64_kernel<1>, dim3(8, 32), dim3(256), 0, stream,
                     Aout, Wto, b_out, (void*)d_out);
}

// Round 18
// 155.486 us; speedup vs baseline: 1.0719x; 1.0063x over previous
//
#include <hip/hip_runtime.h>
#include <stdint.h>

#define DEVI __device__ __forceinline__

constexpr int Bb = 2, NQ = 1024, S = 4096, H = 1024, NH = 16, HD = 64;
constexpr int NSPLIT = 4, SLEN = S / NSPLIT;

typedef __bf16 bf16x8 __attribute__((ext_vector_type(8)));
typedef float f32x4 __attribute__((ext_vector_type(4)));
typedef int i32x4 __attribute__((ext_vector_type(4)));
typedef unsigned short u16;
typedef u16 u16x8 __attribute__((ext_vector_type(8)));

DEVI u16 f2bf(float f) {
  union { float f; unsigned u; } v; v.f = f;
  unsigned r = (v.u + 0x7fffu + ((v.u >> 16) & 1u)) >> 16;
  return (u16)r;
}

DEVI float bf2f(u16 x) {
  union { unsigned u; float f; } v; v.u = ((unsigned)x) << 16;
  return v.f;
}

DEVI float fexp2(float x) {
#if __has_builtin(__builtin_amdgcn_exp2f)
  return __builtin_amdgcn_exp2f(x);
#else
  return exp2f(x);
#endif
}

DEVI void gload_lds16(const void* g, void* lds) {
  __builtin_amdgcn_global_load_lds(
      (const __attribute__((address_space(1))) void*)(uintptr_t)g,
      (__attribute__((address_space(3))) void*)(uint32_t)(uintptr_t)lds,
      16, 0, 0);
}

// ---------------- fused prep: mask->f32 bias | LN(q) | LN(kv) | W^T --------
DEVI void ln_body(const float* __restrict__ x, const float* __restrict__ gamma,
                  const float* __restrict__ beta, u16* __restrict__ out, int row) {
  int lane = threadIdx.x & 63;
  const float4* xr = (const float4*)(x + (size_t)row * H);
  float4 v[4];
  float s = 0.f, s2 = 0.f;
#pragma unroll
  for (int i = 0; i < 4; ++i) {
    v[i] = xr[lane + i * 64];
    s += v[i].x + v[i].y + v[i].z + v[i].w;
    s2 += v[i].x * v[i].x + v[i].y * v[i].y + v[i].z * v[i].z + v[i].w * v[i].w;
  }
#pragma unroll
  for (int d = 1; d < 64; d <<= 1) { s += __shfl_xor(s, d); s2 += __shfl_xor(s2, d); }
  float mu = s * (1.f / H);
  float rstd = rsqrtf(s2 * (1.f / H) - mu * mu + 1e-6f);
  u16* orow = out + (size_t)row * H;
  const float4* g4 = (const float4*)gamma;
  const float4* b4 = (const float4*)beta;
#pragma unroll
  for (int i = 0; i < 4; ++i) {
    float4 g = g4[lane + i * 64], bb = b4[lane + i * 64];
    ushort4 o;
    o.x = f2bf((v[i].x - mu) * rstd * g.x + bb.x);
    o.y = f2bf((v[i].y - mu) * rstd * g.y + bb.y);
    o.z = f2bf((v[i].z - mu) * rstd * g.z + bb.z);
    o.w = f2bf((v[i].w - mu) * rstd * g.w + bb.w);
    *(ushort4*)(orow + (size_t)(lane + i * 64) * 4) = o;
  }
}

__global__ __launch_bounds__(256) void prep_kernel(
    const unsigned char* __restrict__ mraw, float* __restrict__ maskF,
    const float* __restrict__ queries, const float* __restrict__ keys_values,
    const float* __restrict__ gamma, const float* __restrict__ beta,
    u16* __restrict__ Xq, u16* __restrict__ Xkv,
    const float* __restrict__ W_qkv, const float* __restrict__ W_out,
    u16* __restrict__ Wtq, u16* __restrict__ Wto) {
  __shared__ int isByte;
  __shared__ float tile[32][33];
  const int b = blockIdx.x;
  if (b == 0) {
    if (threadIdx.x == 0) isByte = 0;
    __syncthreads();
    int any = 0;
    for (int p = threadIdx.x; p < Bb * S; p += 256)
      if ((p & 3) && mraw[p]) any = 1;
    if (any) atomicOr(&isByte, 1);
    __syncthreads();
    const int bytemode = isByte;
    for (int i = threadIdx.x; i < Bb * S; i += 256) {
      bool on = bytemode ? (mraw[i] != 0) : (((const int*)mraw)[i] != 0);
      maskF[i] = on ? 0.f : -1e30f;
    }
  } else if (b < 513) {
    ln_body(queries, gamma, beta, Xq, (b - 1) * 4 + (threadIdx.x >> 6));
  } else if (b < 2561) {
    ln_body(keys_values, gamma, beta, Xkv, (b - 513) * 4 + (threadIdx.x >> 6));
  } else {
    const float* in; u16* out; int C, t;
    if (b < 5633) { t = b - 2561; in = W_qkv; out = Wtq; C = 3 * H; }
    else          { t = b - 5633; in = W_out; out = Wto; C = H; }
    const int nbx = C / 32;
    int c0 = (t % nbx) * 32, r0 = (t / nbx) * 32;
    int tx = threadIdx.x & 31, ty = threadIdx.x >> 5;
#pragma unroll
    for (int i = 0; i < 32; i += 8)
      tile[ty + i][tx] = in[(size_t)(r0 + ty + i) * C + c0 + tx];
    __syncthreads();
#pragma unroll
    for (int i = 0; i < 32; i += 8)
      out[(size_t)(c0 + ty + i) * H + r0 + tx] = f2bf(tile[tx][ty + i]);
  }
}

// ---------- KV projection GEMM: 256^2, BK=32, 4-buffer counted-vmcnt ring --
__global__ __launch_bounds__(512, 2) void gemm_kv_kernel(
    const u16* __restrict__ Xkv, const u16* __restrict__ WtqKV,
    const float* __restrict__ bias, u16* __restrict__ KVbuf) {
  __shared__ __align__(16) u16 Abuf[4][256 * 32];
  __shared__ __align__(16) u16 Bbuf[4][256 * 32];
  const int tid = threadIdx.x, wid = tid >> 6, lane = tid & 63;
  const int fr = lane & 15, fq = lane >> 4;
  const int wr = (wid >> 2) * 128, wc = (wid & 3) * 64;
  const int bid = blockIdx.x;
  const int xcd = bid & 7, loc = bid >> 3;
  const int by = xcd * 4 + (loc & 3), bx = loc >> 2;  // by:0..31, bx:0..7
  const u16* Ag = Xkv + (size_t)(by * 256) * 1024;
  const u16* Bg = WtqKV + (size_t)(bx * 256) * 1024;

  f32x4 acc[8][4] = {};

  auto stage = [&](int tt) {
    const int k0 = tt * 32;
    u16* Ad = &Abuf[tt & 3][0];
    u16* Bd = &Bbuf[tt & 3][0];
#pragma unroll
    for (int l = 0; l < 2; ++l) {
      int ci = tid + l * 512;
      int row = ci >> 2, ch = ci & 3;
      int chs = ch ^ ((row >> 1) & 3);
      gload_lds16(Ag + (size_t)row * 1024 + k0 + chs * 8, Ad + ci * 8);
      gload_lds16(Bg + (size_t)row * 1024 + k0 + chs * 8, Bd + ci * 8);
    }
  };

#define KV_ITER(T, VM)                                                          \
  {                                                                             \
    asm volatile("s_waitcnt vmcnt(" #VM ")" ::: "memory");                      \
    __syncthreads();                                                            \
    const u16* Ac = &Abuf[(T) & 3][0];                                          \
    const u16* Bc = &Bbuf[(T) & 3][0];                                          \
    bf16x8 af[8], bfv[4];                                                       \
    _Pragma("unroll") for (int m = 0; m < 8; ++m) {                             \
      int row = wr + m * 16 + fr;                                               \
      af[m] = *(const bf16x8*)(Ac + row * 32 + (fq ^ ((row >> 1) & 3)) * 8);    \
    }                                                                           \
    _Pragma("unroll") for (int n = 0; n < 4; ++n) {                             \
      int row = wc + n * 16 + fr;                                               \
      bfv[n] = *(const bf16x8*)(Bc + row * 32 + (fq ^ ((row >> 1) & 3)) * 8);   \
    }                                                                           \
    if ((T) + 3 < 32) stage((T) + 3);                                           \
    __builtin_amdgcn_s_setprio(1);                                              \
    _Pragma("unroll") for (int m = 0; m < 8; ++m)                               \
      _Pragma("unroll") for (int n = 0; n < 4; ++n)                             \
        acc[m][n] = __builtin_amdgcn_mfma_f32_16x16x32_bf16(af[m], bfv[n], acc[m][n], 0, 0, 0); \
    __builtin_amdgcn_s_setprio(0);                                              \
  }

  stage(0);
  stage(1);
  stage(2);
  for (int t = 0; t < 29; ++t) KV_ITER(t, 8)
  KV_ITER(29, 8)
  KV_ITER(30, 4)
  KV_ITER(31, 0)
#undef KV_ITER

#pragma unroll
  for (int m = 0; m < 8; ++m)
#pragma unroll
    for (int n = 0; n < 4; ++n) {
      const int c = bx * 256 + wc + n * 16 + fr;
      const int r0 = by * 256 + wr + m * 16 + fq * 4;
      const float bv = bias[c];
      if (c >= 1024) {  // V^T [B][NH][HD][S]
        int bb = r0 >> 12, kv = r0 & (S - 1);
        int cc = c - 1024, head = cc >> 6, d = cc & 63;
        ushort4 o;
        o.x = f2bf(acc[m][n][0] + bv);
        o.y = f2bf(acc[m][n][1] + bv);
        o.z = f2bf(acc[m][n][2] + bv);
        o.w = f2bf(acc[m][n][3] + bv);
        u16* vb = KVbuf + (size_t)Bb * NH * S * HD;
        *(ushort4*)(vb + (((size_t)(bb * NH + head)) * HD + d) * S + kv) = o;
      } else {  // K [B][NH][S][HD]
#pragma unroll
        for (int i = 0; i < 4; ++i) {
          int r = r0 + i;
          KVbuf[((((size_t)(r >> 12)) * NH + (c >> 6)) * S + (r & (S - 1))) * HD + (c & 63)] =
              f2bf(acc[m][n][i] + bv);
        }
      }
    }
}

// ------- 64x128 ring GEMM (BK=32, 4-buffer, vmcnt 6/3/0), two epilogues ----
template <int EPI>
__global__ __launch_bounds__(256, 3) void gemm64_kernel(
    const u16* __restrict__ A, const u16* __restrict__ Bt,
    const float* __restrict__ bias, void* __restrict__ outp) {
  __shared__ __align__(16) u16 Abuf[4][64 * 32];
  __shared__ __align__(16) u16 Bbuf[4][128 * 32];
  const int tid = threadIdx.x, wid = tid >> 6, lane = tid & 63;
  const int fr = lane & 15, fq = lane >> 4;
  const int wr = (wid >> 1) * 32, wc = (wid & 1) * 64;
  const int brow = blockIdx.y * 64, bcol = blockIdx.x * 128;
  const u16* Ag = A + (size_t)brow * 1024;
  const u16* Bg = Bt + (size_t)bcol * 1024;

  f32x4 acc[2][4] = {};

  auto stage = [&](int tt) {
    const int k0 = tt * 32;
    u16* Ad = &Abuf[tt & 3][0];
    u16* Bd = &Bbuf[tt & 3][0];
    {
      int row = tid >> 2, ch = tid & 3;
      int chs = ch ^ ((row >> 1) & 3);
      gload_lds16(Ag + (size_t)row * 1024 + k0 + chs * 8, Ad + tid * 8);
    }
#pragma unroll
    for (int l = 0; l < 2; ++l) {
      int ci = tid + l * 256;
      int row = ci >> 2, ch = ci & 3;
      int chs = ch ^ ((row >> 1) & 3);
      gload_lds16(Bg + (size_t)row * 1024 + k0 + chs * 8, Bd + ci * 8);
    }
  };

#define G64_ITER(T, VM)                                                         \
  {                                                                             \
    asm volatile("s_waitcnt vmcnt(" #VM ")" ::: "memory");                      \
    __syncthreads();                                                            \
    const u16* Ac = &Abuf[(T) & 3][0];                                          \
    const u16* Bc = &Bbuf[(T) & 3][0];                                          \
    bf16x8 af[2], bfv[4];                                                       \
    _Pragma("unroll") for (int m = 0; m < 2; ++m) {                             \
      int row = wr + m * 16 + fr;                                               \
      af[m] = *(const bf16x8*)(Ac + row * 32 + (fq ^ ((row >> 1) & 3)) * 8);    \
    }                                                                           \
    _Pragma("unroll") for (int n = 0; n < 4; ++n) {                             \
      int row = wc + n * 16 + fr;                                               \
      bfv[n] = *(const bf16x8*)(Bc + row * 32 + (fq ^ ((row >> 1) & 3)) * 8);   \
    }                                                                           \
    if ((T) + 3 < 32) stage((T) + 3);                                           \
    __builtin_amdgcn_s_setprio(1);                                              \
    _Pragma("unroll") for (int m = 0; m < 2; ++m)                               \
      _Pragma("unroll") for (int n = 0; n < 4; ++n)                             \
        acc[m][n] = __builtin_amdgcn_mfma_f32_16x16x32_bf16(af[m], bfv[n], acc[m][n], 0, 0, 0); \
    __builtin_amdgcn_s_setprio(0);                                              \
  }

  stage(0);
  stage(1);
  stage(2);
  for (int t = 0; t < 29; ++t) G64_ITER(t, 6)
  G64_ITER(29, 6)
  G64_ITER(30, 3)
  G64_ITER(31, 0)
#undef G64_ITER

  constexpr float QSCALE = 0.125f * 1.4426950408889634f;
#pragma unroll
  for (int m = 0; m < 2; ++m)
#pragma unroll
    for (int n = 0; n < 4; ++n) {
      const int c = bcol + wc + n * 16 + fr;
      const int r0 = brow + wr + m * 16 + fq * 4;
      const float bv = bias[c];
#pragma unroll
      for (int i = 0; i < 4; ++i) {
        int r = r0 + i;
        float val = acc[m][n][i] + bv;
        if constexpr (EPI == 0) {
          ((u16*)outp)[((((size_t)(r >> 10)) * NH + (c >> 6)) * NQ + (r & (NQ - 1))) * HD + (c & 63)] =
              f2bf(val * QSCALE);
        } else {
          ((float*)outp)[(size_t)r * H + c] = val;
        }
      }
    }
}

// -------- flash attention: 8 waves, QBLK=256, 2 q-groups/wave, KVBLK=64 ----
// 4-deep K/V/mask ring with counted vmcnt(4): all per-tile VMEM traffic
// (K, V, mask) goes through global_load_lds so the static count is exact.
// stage(t+3) issued after iter-t barrier (its target buf[(t-1)&3]'s readers
// all passed that barrier). Loads span barriers (T4); drain amortized.
__global__ __launch_bounds__(512, 4) void attn_kernel(
    const u16* __restrict__ Qb, const u16* __restrict__ Kb,
    const u16* __restrict__ Vt, const float* __restrict__ maskF,
    u16* __restrict__ Opart, float2* __restrict__ ml) {
  __shared__ __align__(16) char smem[66560];
  u16* Ktile = (u16*)smem;                 // [4][64*64]
  u16* Vtile = (u16*)(smem + 32768);       // [4][64*64]
  float* Mb = (float*)(smem + 65536);      // [4][64]
  const int bflat = blockIdx.x;
  const int r = bflat & 7, idx = bflat >> 3;
  const int q0 = (idx & 3) * 256;
  const int g = (idx >> 2) * 8 + r;
  const int bh = g & 31, z = g >> 5;
  const int b = bh >> 4, kv0 = z * SLEN;
  const int tid = threadIdx.x, w = tid >> 6, lane = tid & 63;
  const int fr = lane & 15, fq = lane >> 4, fr7 = fr & 7;
  const u16* QgA = Qb + ((size_t)bh * NQ + q0 + w * 32) * HD;
  const u16* QgB = QgA + 16 * HD;
  const u16* Kg = Kb + (size_t)bh * S * HD;
  const u16* Vg = Vt + (size_t)bh * HD * S;
  const float* mgs = maskF + (size_t)b * S + kv0;

  const int rs = tid >> 3, gs = (tid & 7) ^ (rs & 7);

  bf16x8 qfA0 = *(const bf16x8*)(QgA + fr * HD + fq * 8);
  bf16x8 qfA1 = *(const bf16x8*)(QgA + fr * HD + 32 + fq * 8);
  bf16x8 qfB0 = *(const bf16x8*)(QgB + fr * HD + fq * 8);
  bf16x8 qfB1 = *(const bf16x8*)(QgB + fr * HD + 32 + fq * 8);

  const int A0 = ((((fq << 1)) & 3) * 16 + fr) << 2;
  const int A1 = ((((fq << 1) + 1) & 3) * 16 + fr) << 2;
  const bool lofq = (fq < 2);

  f32x4 oaccA[4] = {}, oaccB[4] = {};
  float mrowA = -1e30f, lrowA = 0.f, mrowB = -1e30f, lrowB = 0.f;

  auto stageKV = [&](int t) {
    const int kts = t * 64, buf = t & 3;
    gload_lds16(Kg + (size_t)(kv0 + kts + rs) * HD + gs * 8, Ktile + buf * 4096 + tid * 8);
    gload_lds16(Vg + (size_t)rs * S + kv0 + kts + gs * 8, Vtile + buf * 4096 + tid * 8);
    if (tid < 16)
      gload_lds16(mgs + kts + tid * 4, Mb + buf * 64 + tid * 4);
  };

  // prologue: 3 tiles in flight
  stageKV(0);
  stageKV(1);
  stageKV(2);

  for (int t = 0; t < SLEN / 64; ++t) {
    // tile t complete when only tiles t+1,t+2 (2 gloads each) remain in flight
    asm volatile("s_waitcnt vmcnt(4)" ::: "memory");
    __syncthreads();
    if (t + 3 < SLEN / 64) stageKV(t + 3);

    const u16* Kc = Ktile + (t & 3) * 4096;
    const u16* Vc = Vtile + (t & 3) * 4096;
    const float* Mc = Mb + (t & 3) * 64;

    float svA[4][4], svB[4][4];
    __builtin_amdgcn_s_setprio(1);
#pragma unroll
    for (int nt = 0; nt < 4; ++nt) {
      const u16* kb2 = Kc + (nt * 16 + fr) * 64;
      bf16x8 k0v = *(const bf16x8*)(kb2 + ((fq) ^ fr7) * 8);
      bf16x8 k1v = *(const bf16x8*)(kb2 + ((4 + fq) ^ fr7) * 8);
      f32x4 tA = {}, tB = {};
      tA = __builtin_amdgcn_mfma_f32_16x16x32_bf16(k0v, qfA0, tA, 0, 0, 0);
      tA = __builtin_amdgcn_mfma_f32_16x16x32_bf16(k1v, qfA1, tA, 0, 0, 0);
      tB = __builtin_amdgcn_mfma_f32_16x16x32_bf16(k0v, qfB0, tB, 0, 0, 0);
      tB = __builtin_amdgcn_mfma_f32_16x16x32_bf16(k1v, qfB1, tB, 0, 0, 0);
      float4 mb = *(const float4*)&Mc[nt * 16 + fq * 4];
      svA[nt][0] = tA[0] + mb.x; svA[nt][1] = tA[1] + mb.y;
      svA[nt][2] = tA[2] + mb.z; svA[nt][3] = tA[3] + mb.w;
      svB[nt][0] = tB[0] + mb.x; svB[nt][1] = tB[1] + mb.y;
      svB[nt][2] = tB[2] + mb.z; svB[nt][3] = tB[3] + mb.w;
    }
    __builtin_amdgcn_s_setprio(0);

    float pmaxA, pmaxB;
    {
      float a0 = fmaxf(fmaxf(svA[0][0], svA[0][1]), fmaxf(svA[0][2], svA[0][3]));
      float a1 = fmaxf(fmaxf(svA[1][0], svA[1][1]), fmaxf(svA[1][2], svA[1][3]));
      float a2 = fmaxf(fmaxf(svA[2][0], svA[2][1]), fmaxf(svA[2][2], svA[2][3]));
      float a3 = fmaxf(fmaxf(svA[3][0], svA[3][1]), fmaxf(svA[3][2], svA[3][3]));
      pmaxA = fmaxf(fmaxf(a0, a1), fmaxf(a2, a3));
      float b0 = fmaxf(fmaxf(svB[0][0], svB[0][1]), fmaxf(svB[0][2], svB[0][3]));
      float b1 = fmaxf(fmaxf(svB[1][0], svB[1][1]), fmaxf(svB[1][2], svB[1][3]));
      float b2 = fmaxf(fmaxf(svB[2][0], svB[2][1]), fmaxf(svB[2][2], svB[2][3]));
      float b3 = fmaxf(fmaxf(svB[3][0], svB[3][1]), fmaxf(svB[3][2], svB[3][3]));
      pmaxB = fmaxf(fmaxf(b0, b1), fmaxf(b2, b3));
    }
    if (__any(pmaxA > mrowA + 12.f)) {
      pmaxA = fmaxf(pmaxA, __shfl_xor(pmaxA, 16));
      pmaxA = fmaxf(pmaxA, __shfl_xor(pmaxA, 32));
      float nm = fmaxf(mrowA, pmaxA);
      float al = fexp2(mrowA - nm);
      mrowA = nm; lrowA *= al;
#pragma unroll
      for (int nt = 0; nt < 4; ++nt)
#pragma unroll
        for (int i = 0; i < 4; ++i) oaccA[nt][i] *= al;
    }
    if (__any(pmaxB > mrowB + 12.f)) {
      pmaxB = fmaxf(pmaxB, __shfl_xor(pmaxB, 16));
      pmaxB = fmaxf(pmaxB, __shfl_xor(pmaxB, 32));
      float nm = fmaxf(mrowB, pmaxB);
      float al = fexp2(mrowB - nm);
      mrowB = nm; lrowB *= al;
#pragma unroll
      for (int nt = 0; nt < 4; ++nt)
#pragma unroll
        for (int i = 0; i < 4; ++i) oaccB[nt][i] *= al;
    }

    float pA[4][4], pB[4][4];
#pragma unroll
    for (int nt = 0; nt < 4; ++nt)
#pragma unroll
      for (int i = 0; i < 4; ++i) {
        pA[nt][i] = fexp2(svA[nt][i] - mrowA);
        pB[nt][i] = fexp2(svB[nt][i] - mrowB);
      }
    {
      float s0 = (pA[0][0] + pA[0][1]) + (pA[0][2] + pA[0][3]);
      float s1 = (pA[1][0] + pA[1][1]) + (pA[1][2] + pA[1][3]);
      float s2 = (pA[2][0] + pA[2][1]) + (pA[2][2] + pA[2][3]);
      float s3 = (pA[3][0] + pA[3][1]) + (pA[3][2] + pA[3][3]);
      lrowA += (s0 + s1) + (s2 + s3);
      float t0 = (pB[0][0] + pB[0][1]) + (pB[0][2] + pB[0][3]);
      float t1 = (pB[1][0] + pB[1][1]) + (pB[1][2] + pB[1][3]);
      float t2 = (pB[2][0] + pB[2][1]) + (pB[2][2] + pB[2][3]);
      float t3 = (pB[3][0] + pB[3][1]) + (pB[3][2] + pB[3][3]);
      lrowB += (t0 + t1) + (t2 + t3);
    }

    int pkA[4][2], pkB[4][2];
#pragma unroll
    for (int nt = 0; nt < 4; ++nt) {
      asm("v_cvt_pk_bf16_f32 %0, %1, %2" : "=v"(pkA[nt][0]) : "v"(pA[nt][0]), "v"(pA[nt][1]));
      asm("v_cvt_pk_bf16_f32 %0, %1, %2" : "=v"(pkA[nt][1]) : "v"(pA[nt][2]), "v"(pA[nt][3]));
      asm("v_cvt_pk_bf16_f32 %0, %1, %2" : "=v"(pkB[nt][0]) : "v"(pB[nt][0]), "v"(pB[nt][1]));
      asm("v_cvt_pk_bf16_f32 %0, %1, %2" : "=v"(pkB[nt][1]) : "v"(pB[nt][2]), "v"(pB[nt][3]));
    }

#pragma unroll
    for (int b2 = 0; b2 < 2; ++b2) {
      i32x4 wvA, wvB;
      {
        int w0a = __builtin_amdgcn_ds_bpermute(A0, pkA[2 * b2][0]);
        int w0b = __builtin_amdgcn_ds_bpermute(A0, pkA[2 * b2 + 1][0]);
        int w1a = __builtin_amdgcn_ds_bpermute(A0, pkA[2 * b2][1]);
        int w1b = __builtin_amdgcn_ds_bpermute(A0, pkA[2 * b2 + 1][1]);
        int w2a = __builtin_amdgcn_ds_bpermute(A1, pkA[2 * b2][0]);
        int w2b = __builtin_amdgcn_ds_bpermute(A1, pkA[2 * b2 + 1][0]);
        int w3a = __builtin_amdgcn_ds_bpermute(A1, pkA[2 * b2][1]);
        int w3b = __builtin_amdgcn_ds_bpermute(A1, pkA[2 * b2 + 1][1]);
        wvA[0] = lofq ? w0a : w0b;
        wvA[1] = lofq ? w1a : w1b;
        wvA[2] = lofq ? w2a : w2b;
        wvA[3] = lofq ? w3a : w3b;
      }
      {
        int w0a = __builtin_amdgcn_ds_bpermute(A0, pkB[2 * b2][0]);
        int w0b = __builtin_amdgcn_ds_bpermute(A0, pkB[2 * b2 + 1][0]);
        int w1a = __builtin_amdgcn_ds_bpermute(A0, pkB[2 * b2][1]);
        int w1b = __builtin_amdgcn_ds_bpermute(A0, pkB[2 * b2 + 1][1]);
        int w2a = __builtin_amdgcn_ds_bpermute(A1, pkB[2 * b2][0]);
        int w2b = __builtin_amdgcn_ds_bpermute(A1, pkB[2 * b2 + 1][0]);
        int w3a = __builtin_amdgcn_ds_bpermute(A1, pkB[2 * b2][1]);
        int w3b = __builtin_amdgcn_ds_bpermute(A1, pkB[2 * b2 + 1][1]);
        wvB[0] = lofq ? w0a : w0b;
        wvB[1] = lofq ? w1a : w1b;
        wvB[2] = lofq ? w2a : w2b;
        wvB[3] = lofq ? w3a : w3b;
      }
      bf16x8 pfragA = __builtin_bit_cast(bf16x8, wvA);
      bf16x8 pfragB = __builtin_bit_cast(bf16x8, wvB);
      __builtin_amdgcn_s_setprio(1);
#pragma unroll
      for (int nt = 0; nt < 4; ++nt) {
        const u16* vb2 = Vc + (nt * 16 + fr) * 64;
        bf16x8 vf = *(const bf16x8*)(vb2 + ((b2 * 4 + fq) ^ fr7) * 8);
        oaccA[nt] = __builtin_amdgcn_mfma_f32_16x16x32_bf16(vf, pfragA, oaccA[nt], 0, 0, 0);
        oaccB[nt] = __builtin_amdgcn_mfma_f32_16x16x32_bf16(vf, pfragB, oaccB[nt], 0, 0, 0);
      }
      __builtin_amdgcn_s_setprio(0);
    }

    __syncthreads();
  }

  lrowA += __shfl_xor(lrowA, 16);
  lrowA += __shfl_xor(lrowA, 32);
  lrowB += __shfl_xor(lrowB, 16);
  lrowB += __shfl_xor(lrowB, 32);
  if (fq == 0) {
    ml[((size_t)z * 32 + bh) * NQ + q0 + w * 32 + fr] = float2{mrowA, lrowA};
    ml[((size_t)z * 32 + bh) * NQ + q0 + w * 32 + 16 + fr] = float2{mrowB, lrowB};
  }

  __syncthreads();  // all tile reads done before epilogue reuses smem
  float* tb = (float*)smem + w * 1088;
  const int qloc = lane >> 2, dl = lane & 3;
#pragma unroll
  for (int gsel = 0; gsel < 2; ++gsel) {
    const f32x4* oc = gsel ? oaccB : oaccA;
#pragma unroll
    for (int nt = 0; nt < 4; ++nt)
#pragma unroll
      for (int i = 0; i < 4; ++i)
        tb[fr * 68 + nt * 16 + fq * 4 + i] = oc[nt][i];
    const float* trow = tb + qloc * 68 + dl * 16;
    u16* gdst = Opart +
        (((size_t)z * 32 + bh) * NQ + q0 + w * 32 + gsel * 16 + qloc) * 64 + dl * 16;
    u16x8 o0, o1;
#pragma unroll
    for (int j = 0; j < 8; ++j) {
      o0[j] = f2bf(trow[j]);
      o1[j] = f2bf(trow[8 + j]);
    }
    *(u16x8*)gdst = o0;
    *(u16x8*)(gdst + 8) = o1;
  }
}

// ---------------- combine split partials -> bf16 Aout ----------------------
__global__ __launch_bounds__(256) void combine_kernel(
    const u16* __restrict__ Opart, const float2* __restrict__ ml,
    u16* __restrict__ out) {
  const int bh = blockIdx.y, b = bh >> 4, h = bh & 15;
  const int q = blockIdx.x * 64 + (threadIdx.x >> 2);
  const int dl = threadIdx.x & 3;
  float2 mm[NSPLIT];
  float M = -1e30f;
#pragma unroll
  for (int zz = 0; zz < NSPLIT; ++zz) {
    mm[zz] = ml[((size_t)zz * 32 + bh) * NQ + q];
    M = fmaxf(M, mm[zz].x);
  }
  float wz[NSPLIT], lsum = 0.f;
#pragma unroll
  for (int zz = 0; zz < NSPLIT; ++zz) {
    wz[zz] = fexp2(mm[zz].x - M);
    lsum += mm[zz].y * wz[zz];
  }
  const float inv = 1.f / lsum;
  float acc[16] = {};
#pragma unroll
  for (int zz = 0; zz < NSPLIT; ++zz) {
    const u16* op = Opart + (((size_t)zz * 32 + bh) * NQ + q) * 64 + dl * 16;
    u16x8 a0 = *(const u16x8*)op;
    u16x8 a1 = *(const u16x8*)(op + 8);
    float wi = wz[zz] * inv;
#pragma unroll
    for (int j = 0; j < 8; ++j) {
      acc[j] += wi * bf2f(a0[j]);
      acc[8 + j] += wi * bf2f(a1[j]);
    }
  }
  u16* orow = out + ((size_t)b * NQ + q) * H + h * HD + dl * 16;
  u16x8 o0, o1;
#pragma unroll
  for (int j = 0; j < 8; ++j) {
    o0[j] = f2bf(acc[j]);
    o1[j] = f2bf(acc[8 + j]);
  }
  *(u16x8*)orow = o0;
  *(u16x8*)(orow + 8) = o1;
}

// ---------------------------------------------------------------------------
extern "C" void kernel_launch(void* const* d_in, const int* in_sizes, int n_in,
                              void* d_out, int out_size, void* d_ws, size_t ws_size,
                              hipStream_t stream) {
  const float* queries = (const float*)d_in[0];
  const float* keys_values = (const float*)d_in[1];
  const void* amask = d_in[2];
  const float* W_qkv = (const float*)d_in[3];
  const float* b_qkv = (const float*)d_in[4];
  const float* W_out = (const float*)d_in[5];
  const float* b_out = (const float*)d_in[6];
  const float* gamma = (const float*)d_in[7];
  const float* beta = (const float*)d_in[8];

  char* ws = (char*)d_ws;
  float* maskF = (float*)ws;                                 // 32 KB f32 bias
  u16* Xq = (u16*)(ws + 32768);                              // [2048][1024]
  u16* Xkv = Xq + (size_t)Bb * NQ * H;                       // [8192][1024]
  u16* Wtq = Xkv + (size_t)Bb * S * H;                       // [3072][1024]
  u16* Wto = Wtq + (size_t)3 * H * H;                        // [1024][1024]
  u16* Qbuf = Wto + (size_t)H * H;                           // [B][NH][NQ][HD]
  u16* Kbuf = Qbuf + (size_t)Bb * NQ * H;                    // [B][NH][S][HD]; V^T follows
  u16* Aout = Kbuf + (size_t)2 * Bb * S * H;                 // [2048][1024]
  u16* Opart = (u16*)(ws + 32768);                           // 16 MB bf16 overlay
  float2* ml = (float2*)((char*)Opart + (size_t)NSPLIT * 32 * NQ * 64 * 2);  // 1 MB

  hipLaunchKernelGGL(prep_kernel, dim3(6657), dim3(256), 0, stream,
                     (const unsigned char*)amask, maskF, queries, keys_values,
                     gamma, beta, Xq, Xkv, W_qkv, W_out, Wtq, Wto);
  hipLaunchKernelGGL(gemm_kv_kernel, dim3(256), dim3(512), 0, stream,
                     Xkv, Wtq + (size_t)H * H, b_qkv + H, Kbuf);
  hipLaunchKernelGGL(gemm64_kernel<0>, dim3(8, 32), dim3(256), 0, stream,
                     Xq, Wtq, b_qkv, (void*)Qbuf);
  hipLaunchKernelGGL(attn_kernel, dim3(NQ / 256 * Bb * NH * NSPLIT), dim3(512), 0, stream,
                     Qbuf, Kbuf, Kbuf + (size_t)Bb * S * H, maskF, Opart, ml);
  hipLaunchKernelGGL(combine_kernel, dim3(NQ / 64, Bb * NH), dim3(256), 0, stream,
                     Opart, ml, Aout);
  hipLaunchKernelGGL(gemm64_kernel<1>, dim3(8, 32), dim3(256), 0, stream,
                     Aout, Wto, b_out, (void*)d_out);
}